// Round 7
// baseline (1048.529 us; speedup 1.0000x reference)
//
#include <hip/hip_runtime.h>
#include <hip/hip_bf16.h>
#include <cstdint>

// Problem constants (fixed by the reference).
static constexpr int N = 100000;
static constexpr int E = 3200000;
static constexpr float BN_EPS = 1e-5f;
static constexpr int NBUCK = (N + 127) >> 7;   // 782 buckets of 128 nodes
static constexpr int NBLK = 256;               // edge-counting blocks
static constexpr int CHUNK = E / NBLK;         // 12500 edges per block (exact)
static constexpr int PARTS = 256;              // node partitions for aggregation
static constexpr int AGG_BLOCKS = PARTS * 8;   // 2048: slice = blk&7 (XCD), part = blk>>3
static constexpr int NWAVE = PARTS * 4;        // 1024 edge-balanced wave partitions

// ---------------- workspace layout (no zero-init required anywhere) ----------------
static constexpr size_t OFF_TOT_D = 0;              // NBUCK int
static constexpr size_t OFF_TOT_S = 3328;           // NBUCK int
static constexpr size_t OFF_DBASE = 6656;           // NBUCK+1 int
static constexpr size_t OFF_SBASE = 9984;           // NBUCK+1 int
static constexpr size_t OFF_AB1   = 13312;          // 256 f32 (a|c)
static constexpr size_t OFF_AB2   = 14336;          // 256 f32
static constexpr size_t OFF_CVEC  = 15360;          // 128 f32
static constexpr size_t OFF_WT    = 16384;          // 128*128 bf16 (transposed, affine-folded W)
static constexpr size_t OFF_WSRT  = 49152;          // NWAVE+1 int (balanced wave starts)
static constexpr size_t OFF_BNP2  = 82944;          // 64*32 f32
static constexpr size_t OFF_BNP   = 148480;         // AGG_BLOCKS*32 f32 = 256 KB
static constexpr size_t OFF_NORM_S= 2245632;        // N f32
static constexpr size_t OFF_NORM_D= 2645632;        // N f32
static constexpr size_t OFF_RP    = 3045632;        // N+1 int
static constexpr size_t OFF_CNT_D = 3445760;        // NBLK*NBUCK int
static constexpr size_t OFF_CNT_S = 4246528;        // NBLK*NBUCK int
static constexpr size_t OFF_OFFD  = 5047296;        // NBLK*NBUCK int
static constexpr size_t OFF_OFFS  = 5848064;        // NBLK*NBUCK int
static constexpr size_t OFF_COL   = 6648832;        // E int
static constexpr size_t OFF_SRCB  = 19448832;       // E uchar
static constexpr size_t OFF_PAIRS = 22648832;       // E uint (s | dloc<<20)
static constexpr size_t OFF_H     = 35448832;       // sliced: 8 x N x 8 uints (25.6 MB)
static constexpr size_t OFF_T     = 61048832;       // sliced: 25.6 MB (layer3: 8 x N x 4 uints)
static constexpr size_t OFF_Z     = 86648832;       // N*64 f32 (25.6 MB; ws >= 142 MB per R1)

using short8  = __attribute__((ext_vector_type(8))) short;
using float4v = __attribute__((ext_vector_type(4))) float;

__device__ inline float bflo(unsigned v) { return __uint_as_float(v << 16); }
__device__ inline float bfhi(unsigned v) { return __uint_as_float(v & 0xffff0000u); }
__device__ inline unsigned short bfbits(float x) {
    __hip_bfloat16 h = __float2bfloat16(x);
    return *reinterpret_cast<unsigned short*>(&h);
}

// ---- pass 1: per-block privatized bucket histograms (LDS atomics only) ----
__global__ __launch_bounds__(256) void k_count(const int* __restrict__ src,
                                               const int* __restrict__ dst,
                                               int* __restrict__ cnt_s,
                                               int* __restrict__ cnt_d) {
    __shared__ int hs[NBUCK], hd[NBUCK];
    int tid = threadIdx.x, blk = blockIdx.x;
    for (int b = tid; b < NBUCK; b += 256) { hs[b] = 0; hd[b] = 0; }
    __syncthreads();
    int e0 = blk * CHUNK, e1 = min(E, e0 + CHUNK);
    for (int e = e0 + tid; e < e1; e += 256) {
        atomicAdd(&hs[src[e] >> 7], 1);
        atomicAdd(&hd[dst[e] >> 7], 1);
    }
    __syncthreads();
    for (int b = tid; b < NBUCK; b += 256) {
        cnt_s[blk * NBUCK + b] = hs[b];
        cnt_d[blk * NBUCK + b] = hd[b];
    }
}

// ---- pass 2a: per-bucket scan over the 256 counting blocks ----
__global__ __launch_bounds__(256) void k_scanA(const int* __restrict__ cnt,
                                               int* __restrict__ off,
                                               int* __restrict__ tot) {
    __shared__ int sd[256];
    int b = blockIdx.x, tid = threadIdx.x;
    int v = cnt[tid * NBUCK + b];
    sd[tid] = v;
    __syncthreads();
    for (int o = 1; o < 256; o <<= 1) {
        int t = (tid >= o) ? sd[tid - o] : 0;
        __syncthreads();
        sd[tid] += t;
        __syncthreads();
    }
    off[tid * NBUCK + b] = sd[tid] - v;
    if (tid == 255) tot[b] = sd[255];
}

// ---- pass 2b: scan bucket totals -> bases ----
__global__ __launch_bounds__(1024) void k_scanB(const int* __restrict__ tot_d,
                                                const int* __restrict__ tot_s,
                                                int* __restrict__ dbase,
                                                int* __restrict__ sbase) {
    __shared__ int sd[1024], ss[1024];
    int tid = threadIdx.x;
    int vd = (tid < NBUCK) ? tot_d[tid] : 0;
    int vs = (tid < NBUCK) ? tot_s[tid] : 0;
    sd[tid] = vd; ss[tid] = vs;
    __syncthreads();
    for (int o = 1; o < 1024; o <<= 1) {
        int td = (tid >= o) ? sd[tid - o] : 0;
        int ts = (tid >= o) ? ss[tid - o] : 0;
        __syncthreads();
        sd[tid] += td; ss[tid] += ts;
        __syncthreads();
    }
    if (tid < NBUCK) { dbase[tid] = sd[tid] - vd; sbase[tid] = ss[tid] - vs; }
    if (tid == 0) { dbase[NBUCK] = E; sbase[NBUCK] = E; }
}

// ---- pass 3: deterministic-offset scatter (LDS cursors, zero global atomics) ----
__global__ __launch_bounds__(256) void k_scatter(const int* __restrict__ src,
                                                 const int* __restrict__ dst,
                                                 const int* __restrict__ dbase,
                                                 const int* __restrict__ sbase,
                                                 const int* __restrict__ offd,
                                                 const int* __restrict__ offs,
                                                 unsigned* __restrict__ pairs,
                                                 unsigned char* __restrict__ srcb) {
    __shared__ int cd[NBUCK], cs[NBUCK];
    int tid = threadIdx.x, blk = blockIdx.x;
    for (int b = tid; b < NBUCK; b += 256) {
        cd[b] = dbase[b] + offd[blk * NBUCK + b];
        cs[b] = sbase[b] + offs[blk * NBUCK + b];
    }
    __syncthreads();
    int e0 = blk * CHUNK, e1 = min(E, e0 + CHUNK);
    for (int e = e0 + tid; e < e1; e += 256) {
        int s = src[e], d = dst[e];
        int pd = atomicAdd(&cd[d >> 7], 1);
        pairs[pd] = (unsigned)s | ((unsigned)(d & 127) << 20);
        int ps = atomicAdd(&cs[s >> 7], 1);
        srcb[ps] = (unsigned char)(s & 127);
    }
}

// ---- pass 4: per-bucket degrees/norms/rp/col (LDS only) ----
__global__ __launch_bounds__(256) void k_build(const unsigned* __restrict__ pairs,
                                               const unsigned char* __restrict__ srcb,
                                               const int* __restrict__ dbase,
                                               const int* __restrict__ sbase,
                                               int* __restrict__ rp,
                                               float* __restrict__ norm_d,
                                               float* __restrict__ norm_s,
                                               int* __restrict__ col) {
    __shared__ int cnt[128], scn[128], lcur[128];
    int b = blockIdx.x, tid = threadIdx.x, node0 = b << 7;
    int nmax = min(128, N - node0);
    if (tid < 128) cnt[tid] = 0;
    __syncthreads();
    int sb = sbase[b], se = sbase[b + 1];
    for (int e = sb + tid; e < se; e += 256) atomicAdd(&cnt[srcb[e]], 1);
    __syncthreads();
    if (tid < nmax) norm_s[node0 + tid] = rsqrtf(fmaxf((float)cnt[tid], 1.0f));
    __syncthreads();
    if (tid < 128) cnt[tid] = 0;
    __syncthreads();
    int beg = dbase[b], end = dbase[b + 1];
    for (int e = beg + tid; e < end; e += 256) atomicAdd(&cnt[pairs[e] >> 20], 1);
    __syncthreads();
    if (tid < 128) scn[tid] = cnt[tid];
    __syncthreads();
    for (int o = 1; o < 128; o <<= 1) {
        int t = (tid < 128 && tid >= o) ? scn[tid - o] : 0;
        __syncthreads();
        if (tid < 128) scn[tid] += t;
        __syncthreads();
    }
    if (tid < nmax) {
        int excl = beg + scn[tid] - cnt[tid];
        rp[node0 + tid] = excl;
        lcur[tid] = excl;
        norm_d[node0 + tid] = rsqrtf(fmaxf((float)cnt[tid], 1.0f));
    }
    if (b == 0 && tid == 0) rp[N] = E;
    __syncthreads();
    for (int e = beg + tid; e < end; e += 256) {
        unsigned p = pairs[e];
        int pos = atomicAdd(&lcur[p >> 20], 1);
        col[pos] = (int)(p & 0xFFFFFu);
    }
}

// ---- edge-balanced wave partition: wsrt[w] = first node of wave w ----
__global__ __launch_bounds__(256) void k_wpart(const int* __restrict__ rp,
                                               int* __restrict__ wsrt) {
    int w = blockIdx.x * 256 + threadIdx.x;
    if (w > NWAVE) return;
    if (w == 0) { wsrt[0] = 0; return; }
    if (w == NWAVE) { wsrt[NWAVE] = N; return; }
    int t = (int)((long long)w * E / NWAVE);
    int lo = 0, hi = N;
    while (lo < hi) { int mid = (lo + hi) >> 1; if (rp[mid] >= t) hi = mid; else lo = mid + 1; }
    wsrt[w] = lo;
}

// ---- W prep: Wt[n][k] = bf16(a[k]*W[k][n]) (transposed), cvec[n] = sum_k c[k]*W[k][n] ----
template <bool AFFINE>
__global__ __launch_bounds__(64) void k_wprep(const float* __restrict__ W,
                                              const float* __restrict__ ab,
                                              int fout,
                                              unsigned short* __restrict__ Wt,
                                              float* __restrict__ cvec) {
    int n = blockIdx.x, k = threadIdx.x;
    float w0 = W[k * fout + n], w1 = W[(k + 64) * fout + n];
    float a0 = AFFINE ? ab[k] : 1.0f;
    float a1 = AFFINE ? ab[k + 64] : 1.0f;
    Wt[n * 128 + k] = bfbits(a0 * w0);
    Wt[n * 128 + k + 64] = bfbits(a1 * w1);
    float cv = AFFINE ? (ab[128 + k] * w0 + ab[192 + k] * w1) : 0.0f;
    for (int o = 32; o; o >>= 1) cv += __shfl_xor(cv, o);
    if (k == 0) cvec[n] = cv;
}

// ---- MFMA GEMM: out = ns .* (Xbf16 @ Wt^T + cvec); output in SLICED layout ----
// FOUT=128: slice = f>>4 (16 feats, 32B); FOUT=64: slice = f>>3 (8 feats, 16B)
// TIn=float: dense f32 input; TIn=ushort: sliced bf16 input [slice][row][8 uints]
template <typename TIn, int FOUT>
__global__ __launch_bounds__(256) void k_gemm(const TIn* __restrict__ in,
                                              const unsigned short* __restrict__ Wt,
                                              const float* __restrict__ cvec,
                                              const float* __restrict__ ns,
                                              unsigned short* __restrict__ out) {
    constexpr int PK = 72;  // 64 + 8 pad
    __shared__ __align__(16) unsigned short Xs[128 * PK];
    __shared__ __align__(16) unsigned short Wsh[FOUT * PK];
    const int tid = threadIdx.x;
    const int r0 = blockIdx.x * 128;
    const int wave = tid >> 6, lane = tid & 63;
    const int l16 = lane & 15, quad = lane >> 4;
    constexpr int MT = (FOUT == 128) ? 4 : 2;
    constexpr int NT = 4;
    const int wm = (FOUT == 128) ? (wave >> 1) : wave;
    const int wn = (FOUT == 128) ? (wave & 1) : 0;
    const int mbase = wm * (MT * 16);
    const int nbase = wn * 64;

    float4v acc[MT][NT];
#pragma unroll
    for (int mt = 0; mt < MT; ++mt)
#pragma unroll
        for (int nt = 0; nt < NT; ++nt) acc[mt][nt] = (float4v){0.f, 0.f, 0.f, 0.f};

    for (int kb = 0; kb < 128; kb += 64) {
        __syncthreads();
        for (int i = tid; i < 128 * 8; i += 256) {
            int row = i >> 3, j = i & 7;
            int grow = r0 + row;
            if constexpr (sizeof(TIn) == 4) {
                short8 p = {0, 0, 0, 0, 0, 0, 0, 0};
                if (grow < N) {
                    const float* g = (const float*)in + (size_t)grow * 128 + kb + j * 8;
                    float4 f0 = *(const float4*)g;
                    float4 f1 = *(const float4*)(g + 4);
                    p[0] = (short)bfbits(f0.x); p[1] = (short)bfbits(f0.y);
                    p[2] = (short)bfbits(f0.z); p[3] = (short)bfbits(f0.w);
                    p[4] = (short)bfbits(f1.x); p[5] = (short)bfbits(f1.y);
                    p[6] = (short)bfbits(f1.z); p[7] = (short)bfbits(f1.w);
                }
                *(short8*)&Xs[row * PK + j * 8] = p;
            } else {
                uint4 v = make_uint4(0, 0, 0, 0);
                if (grow < N) {
                    int ub = (kb >> 1) + j * 4;  // uint index within the 64-uint row
                    const unsigned* Hu = (const unsigned*)in;
                    v = *(const uint4*)&Hu[(size_t)(ub >> 3) * ((size_t)N * 8)
                                           + (size_t)grow * 8 + (ub & 7)];
                }
                *(uint4*)&Xs[row * PK + j * 8] = v;
            }
        }
        for (int i = tid; i < FOUT * 8; i += 256) {
            int n = i >> 3, j = i & 7;
            uint4 v = *(const uint4*)&Wt[n * 128 + kb + j * 8];
            *(uint4*)&Wsh[n * PK + j * 8] = v;
        }
        __syncthreads();
#pragma unroll
        for (int ks = 0; ks < 64; ks += 32) {
            short8 af[MT], bfr[NT];
#pragma unroll
            for (int mt = 0; mt < MT; ++mt)
                af[mt] = *(const short8*)&Xs[(mbase + mt * 16 + l16) * PK + ks + quad * 8];
#pragma unroll
            for (int nt = 0; nt < NT; ++nt)
                bfr[nt] = *(const short8*)&Wsh[(nbase + nt * 16 + l16) * PK + ks + quad * 8];
#pragma unroll
            for (int mt = 0; mt < MT; ++mt)
#pragma unroll
                for (int nt = 0; nt < NT; ++nt)
                    acc[mt][nt] = __builtin_amdgcn_mfma_f32_16x16x32_bf16(
                        af[mt], bfr[nt], acc[mt][nt], 0, 0, 0);
        }
    }
    float cv[NT];
#pragma unroll
    for (int nt = 0; nt < NT; ++nt) cv[nt] = cvec[nbase + nt * 16 + l16];
#pragma unroll
    for (int mt = 0; mt < MT; ++mt) {
#pragma unroll
        for (int r = 0; r < 4; ++r) {
            int row = r0 + mbase + mt * 16 + quad * 4 + r;
            if (row < N) {
                float s = ns[row];
#pragma unroll
                for (int nt = 0; nt < NT; ++nt) {
                    int f = nbase + nt * 16 + l16;
                    unsigned short val = bfbits((acc[mt][nt][r] + cv[nt]) * s);
                    if (FOUT == 128)
                        out[(size_t)(f >> 4) * ((size_t)N * 16) + (size_t)row * 16 + (f & 15)] = val;
                    else
                        out[(size_t)(f >> 3) * ((size_t)N * 8) + (size_t)row * 8 + (f & 7)] = val;
                }
            }
        }
    }
}

// ------- sliced aggregation (128 feats): slice = blk&7 (XCD-local 3.2MB), part = blk>>3 -------
__global__ __launch_bounds__(256) void k_agg128s(const unsigned* __restrict__ Tu, // [slice][n][8 uints]
                                                 const int* __restrict__ wsrt,
                                                 const int* __restrict__ rp,
                                                 const int* __restrict__ col,
                                                 const float* __restrict__ norm_d,
                                                 const float* __restrict__ bias,
                                                 unsigned* __restrict__ Hu,      // same sliced layout
                                                 float* __restrict__ part) {
    int tid = threadIdx.x, wave = tid >> 6, lane = tid & 63;
    int slice = blockIdx.x & 7, prt = blockIdx.x >> 3;
    int w = prt * 4 + wave;
    int n0 = wsrt[w], n1 = wsrt[w + 1];
    int le = lane >> 3, lu = lane & 7;   // 8 edges/instr, 1 uint (2 feats) per lane
    const unsigned* Ts = Tu + (size_t)slice * ((size_t)N * 8);
    unsigned* Hs = Hu + (size_t)slice * ((size_t)N * 8);
    float bb0 = bias[slice * 16 + lu * 2];
    float bb1 = bias[slice * 16 + lu * 2 + 1];
    float s0 = 0.f, q0 = 0.f, s1 = 0.f, q1 = 0.f;
    for (int n = n0; n < n1; ++n) {
        int beg = rp[n], end = rp[n + 1];
        float a0 = 0.f, a1 = 0.f;
        int e = beg;
        for (; e + 32 <= end; e += 32) {
            int c0 = col[e + le], c1 = col[e + 8 + le];
            int c2 = col[e + 16 + le], c3 = col[e + 24 + le];
            unsigned v0 = Ts[c0 * 8 + lu];
            unsigned v1 = Ts[c1 * 8 + lu];
            unsigned v2 = Ts[c2 * 8 + lu];
            unsigned v3 = Ts[c3 * 8 + lu];
            a0 += bflo(v0) + bflo(v1) + bflo(v2) + bflo(v3);
            a1 += bfhi(v0) + bfhi(v1) + bfhi(v2) + bfhi(v3);
        }
        for (; e + 8 <= end; e += 8) {
            unsigned v = Ts[col[e + le] * 8 + lu];
            a0 += bflo(v); a1 += bfhi(v);
        }
        if (e + le < end) {
            unsigned v = Ts[col[e + le] * 8 + lu];
            a0 += bflo(v); a1 += bfhi(v);
        }
        a0 += __shfl_xor(a0, 8);  a1 += __shfl_xor(a1, 8);
        a0 += __shfl_xor(a0, 16); a1 += __shfl_xor(a1, 16);
        a0 += __shfl_xor(a0, 32); a1 += __shfl_xor(a1, 32);
        float nd = norm_d[n];
        float r0 = fmaxf(a0 * nd + bb0, 0.f);
        float r1 = fmaxf(a1 * nd + bb1, 0.f);
        if (lane < 8) Hs[n * 8 + lu] = ((unsigned)bfbits(r1) << 16) | bfbits(r0);
        s0 += r0; q0 += r0 * r0; s1 += r1; q1 += r1 * r1;
    }
    __shared__ float red[4][32];
    if (lane < 8) {
        red[wave][lu * 4 + 0] = s0;
        red[wave][lu * 4 + 1] = q0;
        red[wave][lu * 4 + 2] = s1;
        red[wave][lu * 4 + 3] = q1;
    }
    __syncthreads();
    if (tid < 32)
        part[blockIdx.x * 32 + tid] = red[0][tid] + red[1][tid] + red[2][tid] + red[3][tid];
}

// BN partial reduce stage 1: 2048 block-rows -> 64 rows (8 chunks per slice)
__global__ __launch_bounds__(64) void k_bnred(const float* __restrict__ part,
                                              float* __restrict__ part2) {
    int g = blockIdx.x, tid = threadIdx.x;
    if (tid >= 32) return;
    int slice = g & 7, chunk = g >> 3;
    float s = 0.f;
    for (int i = 0; i < 32; ++i) {
        int b = (chunk * 32 + i) * 8 + slice;
        s += part[b * 32 + tid];
    }
    part2[g * 32 + tid] = s;
}

// BN final: 64 rows -> folded affine (a|c)
__global__ __launch_bounds__(128) void k_bnfin(const float* __restrict__ part2,
                                               const float* __restrict__ gamma,
                                               const float* __restrict__ beta,
                                               float* __restrict__ ab) {
    int f = threadIdx.x;
    int slice = f >> 4, lu = (f & 15) >> 1, par = f & 1;
    float s = 0.f, q = 0.f;
    for (int chunk = 0; chunk < 8; ++chunk) {
        int g = chunk * 8 + slice;
        s += part2[g * 32 + lu * 4 + par * 2 + 0];
        q += part2[g * 32 + lu * 4 + par * 2 + 1];
    }
    float mu = s * (1.0f / N);
    float var = q * (1.0f / N) - mu * mu;
    float aa = gamma[f] * rsqrtf(var + BN_EPS);
    ab[f] = aa;
    ab[128 + f] = beta[f] - mu * aa;
}

// ------- sliced aggregation (64 feats) -> Z (f32, row-major) -------
__global__ __launch_bounds__(256) void k_agg64s(const unsigned* __restrict__ Tu, // [slice][n][4 uints]
                                                const int* __restrict__ wsrt,
                                                const int* __restrict__ rp,
                                                const int* __restrict__ col,
                                                const float* __restrict__ norm_d,
                                                const float* __restrict__ b3,
                                                float* __restrict__ Z) {
    int tid = threadIdx.x, wave = tid >> 6, lane = tid & 63;
    int slice = blockIdx.x & 7, prt = blockIdx.x >> 3;
    int w = prt * 4 + wave;
    int n0 = wsrt[w], n1 = wsrt[w + 1];
    int le = lane >> 2, lu = lane & 3;   // 16 edges/instr
    const unsigned* Ts = Tu + (size_t)slice * ((size_t)N * 4);
    float bb0 = b3[slice * 8 + lu * 2], bb1 = b3[slice * 8 + lu * 2 + 1];
    for (int n = n0; n < n1; ++n) {
        int beg = rp[n], end = rp[n + 1];
        float a0 = 0.f, a1 = 0.f;
        int e = beg;
        for (; e + 32 <= end; e += 32) {
            int c0 = col[e + le], c1 = col[e + 16 + le];
            unsigned v0 = Ts[c0 * 4 + lu], v1 = Ts[c1 * 4 + lu];
            a0 += bflo(v0) + bflo(v1);
            a1 += bfhi(v0) + bfhi(v1);
        }
        for (; e + 16 <= end; e += 16) {
            unsigned v = Ts[col[e + le] * 4 + lu];
            a0 += bflo(v); a1 += bfhi(v);
        }
        if (e + le < end) {
            unsigned v = Ts[col[e + le] * 4 + lu];
            a0 += bflo(v); a1 += bfhi(v);
        }
        a0 += __shfl_xor(a0, 4);  a1 += __shfl_xor(a1, 4);
        a0 += __shfl_xor(a0, 8);  a1 += __shfl_xor(a1, 8);
        a0 += __shfl_xor(a0, 16); a1 += __shfl_xor(a1, 16);
        a0 += __shfl_xor(a0, 32); a1 += __shfl_xor(a1, 32);
        float nd = norm_d[n];
        if (lane < 4) {
            float2 z = make_float2(a0 * nd + bb0, a1 * nd + bb1);
            *(float2*)&Z[(size_t)n * 64 + slice * 8 + lu * 2] = z;
        }
    }
}

// log_softmax over 64 feats (one wave per node)
__global__ __launch_bounds__(256) void k_lsm(const float* __restrict__ Z,
                                             float* __restrict__ out) {
    int wave = threadIdx.x >> 6, lane = threadIdx.x & 63;
    int n = blockIdx.x * 4 + wave;
    if (n >= N) return;
    float z = Z[(size_t)n * 64 + lane];
    float m = z;
    for (int o = 32; o; o >>= 1) m = fmaxf(m, __shfl_xor(m, o));
    float ex = __expf(z - m);
    float ss = ex;
    for (int o = 32; o; o >>= 1) ss += __shfl_xor(ss, o);
    out[(size_t)n * 64 + lane] = z - m - __logf(ss);
}

extern "C" void kernel_launch(void* const* d_in, const int* in_sizes, int n_in,
                              void* d_out, int out_size, void* d_ws, size_t ws_size,
                              hipStream_t stream) {
    const float* x  = (const float*)d_in[0];
    const int* src  = (const int*)d_in[1];
    const int* dst  = (const int*)d_in[2];
    const float* W1 = (const float*)d_in[3];
    const float* b1 = (const float*)d_in[4];
    const float* W2 = (const float*)d_in[5];
    const float* b2 = (const float*)d_in[6];
    const float* W3 = (const float*)d_in[7];
    const float* b3 = (const float*)d_in[8];
    const float* g1 = (const float*)d_in[9];
    const float* be1= (const float*)d_in[10];
    const float* g2 = (const float*)d_in[11];
    const float* be2= (const float*)d_in[12];
    float* out = (float*)d_out;

    char* ws = (char*)d_ws;
    int* tot_d = (int*)(ws + OFF_TOT_D);
    int* tot_s = (int*)(ws + OFF_TOT_S);
    int* dbase = (int*)(ws + OFF_DBASE);
    int* sbase = (int*)(ws + OFF_SBASE);
    float* ab1 = (float*)(ws + OFF_AB1);
    float* ab2 = (float*)(ws + OFF_AB2);
    float* cvec = (float*)(ws + OFF_CVEC);
    unsigned short* Wt = (unsigned short*)(ws + OFF_WT);
    int* wsrt = (int*)(ws + OFF_WSRT);
    float* bnp2 = (float*)(ws + OFF_BNP2);
    float* bnp = (float*)(ws + OFF_BNP);
    float* norm_s = (float*)(ws + OFF_NORM_S);
    float* norm_d = (float*)(ws + OFF_NORM_D);
    int* rp = (int*)(ws + OFF_RP);
    int* cnt_d = (int*)(ws + OFF_CNT_D);
    int* cnt_s = (int*)(ws + OFF_CNT_S);
    int* offd = (int*)(ws + OFF_OFFD);
    int* offs = (int*)(ws + OFF_OFFS);
    int* col = (int*)(ws + OFF_COL);
    unsigned char* srcb = (unsigned char*)(ws + OFF_SRCB);
    unsigned* pairs = (unsigned*)(ws + OFF_PAIRS);
    unsigned short* H = (unsigned short*)(ws + OFF_H);
    unsigned short* T = (unsigned short*)(ws + OFF_T);
    float* Z = (float*)(ws + OFF_Z);

    // CSR build — zero global atomics
    k_count<<<NBLK, 256, 0, stream>>>(src, dst, cnt_s, cnt_d);
    k_scanA<<<NBUCK, 256, 0, stream>>>(cnt_d, offd, tot_d);
    k_scanA<<<NBUCK, 256, 0, stream>>>(cnt_s, offs, tot_s);
    k_scanB<<<1, 1024, 0, stream>>>(tot_d, tot_s, dbase, sbase);
    k_scatter<<<NBLK, 256, 0, stream>>>(src, dst, dbase, sbase, offd, offs, pairs, srcb);
    k_build<<<NBUCK, 256, 0, stream>>>(pairs, srcb, dbase, sbase, rp, norm_d, norm_s, col);
    k_wpart<<<(NWAVE + 256) / 256, 256, 0, stream>>>(rp, wsrt);

    const int gemm_grid = (N + 127) / 128;

    // Layer 1
    k_wprep<false><<<128, 64, 0, stream>>>(W1, nullptr, 128, Wt, cvec);
    k_gemm<float, 128><<<gemm_grid, 256, 0, stream>>>(x, Wt, cvec, norm_s, T);
    k_agg128s<<<AGG_BLOCKS, 256, 0, stream>>>((const unsigned*)T, wsrt, rp, col, norm_d, b1, (unsigned*)H, bnp);
    k_bnred<<<64, 64, 0, stream>>>(bnp, bnp2);
    k_bnfin<<<1, 128, 0, stream>>>(bnp2, g1, be1, ab1);

    // Layer 2
    k_wprep<true><<<128, 64, 0, stream>>>(W2, ab1, 128, Wt, cvec);
    k_gemm<unsigned short, 128><<<gemm_grid, 256, 0, stream>>>(H, Wt, cvec, norm_s, T);
    k_agg128s<<<AGG_BLOCKS, 256, 0, stream>>>((const unsigned*)T, wsrt, rp, col, norm_d, b2, (unsigned*)H, bnp);
    k_bnred<<<64, 64, 0, stream>>>(bnp, bnp2);
    k_bnfin<<<1, 128, 0, stream>>>(bnp2, g2, be2, ab2);

    // Layer 3 (64 outputs) + log_softmax
    k_wprep<true><<<64, 64, 0, stream>>>(W3, ab2, 64, Wt, cvec);
    k_gemm<unsigned short, 64><<<gemm_grid, 256, 0, stream>>>(H, Wt, cvec, norm_s, T);
    k_agg64s<<<AGG_BLOCKS, 256, 0, stream>>>((const unsigned*)T, wsrt, rp, col, norm_d, b3, Z);
    k_lsm<<<(N + 3) / 4, 256, 0, stream>>>(Z, out);
}

// Round 8
// 724.056 us; speedup vs baseline: 1.4481x; 1.4481x over previous
//
#include <hip/hip_runtime.h>
#include <hip/hip_bf16.h>
#include <cstdint>

// Problem constants (fixed by the reference).
static constexpr int N = 100000;
static constexpr int E = 3200000;
static constexpr float BN_EPS = 1e-5f;
static constexpr int NBUCK = (N + 127) >> 7;   // 782 buckets of 128 nodes
static constexpr int NBLK = 256;               // edge-counting blocks
static constexpr int CHUNK = E / NBLK;         // 12500 edges per block (exact)
static constexpr int AGG_BLOCKS = 2048;        // 8192 waves = 100% occupancy cap
static constexpr int NWAVE = AGG_BLOCKS * 4;   // edge-balanced wave partitions

// ---------------- workspace layout (no zero-init required anywhere) ----------------
static constexpr size_t OFF_TOT_D = 0;              // NBUCK int
static constexpr size_t OFF_TOT_S = 3328;           // NBUCK int
static constexpr size_t OFF_DBASE = 6656;           // NBUCK+1 int
static constexpr size_t OFF_SBASE = 9984;           // NBUCK+1 int
static constexpr size_t OFF_AB1   = 13312;          // 256 f32 (a|c)
static constexpr size_t OFF_AB2   = 14336;          // 256 f32
static constexpr size_t OFF_CVEC  = 15360;          // 128 f32
static constexpr size_t OFF_WT    = 16384;          // 128*128 bf16 (transposed, affine-folded W)
static constexpr size_t OFF_WSRT  = 49152;          // NWAVE+1 int (balanced wave starts)
static constexpr size_t OFF_BNP2  = 82944;          // 64*256 f32
static constexpr size_t OFF_BNP   = 148480;         // AGG_BLOCKS*256 f32 = 2 MB
static constexpr size_t OFF_NORM_S= 2245632;        // N f32
static constexpr size_t OFF_NORM_D= 2645632;        // N f32
static constexpr size_t OFF_RP    = 3045632;        // N+1 int
static constexpr size_t OFF_CNT_D = 3445760;        // NBLK*NBUCK int
static constexpr size_t OFF_CNT_S = 4246528;        // NBLK*NBUCK int
static constexpr size_t OFF_OFFD  = 5047296;        // NBLK*NBUCK int
static constexpr size_t OFF_OFFS  = 5848064;        // NBLK*NBUCK int
static constexpr size_t OFF_COL   = 6648832;        // E int
static constexpr size_t OFF_SRCB  = 19448832;       // E uchar
static constexpr size_t OFF_PAIRS = 22648832;       // E uint (s | dloc<<20)
static constexpr size_t OFF_H     = 35448832;       // N*128 bf16
static constexpr size_t OFF_T     = 61048832;       // N*128 bf16

using short8  = __attribute__((ext_vector_type(8))) short;
using float4v = __attribute__((ext_vector_type(4))) float;

__device__ inline float bflo(unsigned v) { return __uint_as_float(v << 16); }
__device__ inline float bfhi(unsigned v) { return __uint_as_float(v & 0xffff0000u); }
__device__ inline unsigned short bfbits(float x) {
    __hip_bfloat16 h = __float2bfloat16(x);
    return *reinterpret_cast<unsigned short*>(&h);
}

// ---- pass 1: per-block privatized bucket histograms (LDS atomics only) ----
__global__ __launch_bounds__(256) void k_count(const int* __restrict__ src,
                                               const int* __restrict__ dst,
                                               int* __restrict__ cnt_s,
                                               int* __restrict__ cnt_d) {
    __shared__ int hs[NBUCK], hd[NBUCK];
    int tid = threadIdx.x, blk = blockIdx.x;
    for (int b = tid; b < NBUCK; b += 256) { hs[b] = 0; hd[b] = 0; }
    __syncthreads();
    int e0 = blk * CHUNK, e1 = min(E, e0 + CHUNK);
    for (int e = e0 + tid; e < e1; e += 256) {
        atomicAdd(&hs[src[e] >> 7], 1);
        atomicAdd(&hd[dst[e] >> 7], 1);
    }
    __syncthreads();
    for (int b = tid; b < NBUCK; b += 256) {
        cnt_s[blk * NBUCK + b] = hs[b];
        cnt_d[blk * NBUCK + b] = hd[b];
    }
}

// ---- pass 2a: per-bucket scan over the 256 counting blocks ----
__global__ __launch_bounds__(256) void k_scanA(const int* __restrict__ cnt,
                                               int* __restrict__ off,
                                               int* __restrict__ tot) {
    __shared__ int sd[256];
    int b = blockIdx.x, tid = threadIdx.x;
    int v = cnt[tid * NBUCK + b];
    sd[tid] = v;
    __syncthreads();
    for (int o = 1; o < 256; o <<= 1) {
        int t = (tid >= o) ? sd[tid - o] : 0;
        __syncthreads();
        sd[tid] += t;
        __syncthreads();
    }
    off[tid * NBUCK + b] = sd[tid] - v;
    if (tid == 255) tot[b] = sd[255];
}

// ---- pass 2b: scan bucket totals -> bases ----
__global__ __launch_bounds__(1024) void k_scanB(const int* __restrict__ tot_d,
                                                const int* __restrict__ tot_s,
                                                int* __restrict__ dbase,
                                                int* __restrict__ sbase) {
    __shared__ int sd[1024], ss[1024];
    int tid = threadIdx.x;
    int vd = (tid < NBUCK) ? tot_d[tid] : 0;
    int vs = (tid < NBUCK) ? tot_s[tid] : 0;
    sd[tid] = vd; ss[tid] = vs;
    __syncthreads();
    for (int o = 1; o < 1024; o <<= 1) {
        int td = (tid >= o) ? sd[tid - o] : 0;
        int ts = (tid >= o) ? ss[tid - o] : 0;
        __syncthreads();
        sd[tid] += td; ss[tid] += ts;
        __syncthreads();
    }
    if (tid < NBUCK) { dbase[tid] = sd[tid] - vd; sbase[tid] = ss[tid] - vs; }
    if (tid == 0) { dbase[NBUCK] = E; sbase[NBUCK] = E; }
}

// ---- pass 3: deterministic-offset scatter (LDS cursors, zero global atomics) ----
__global__ __launch_bounds__(256) void k_scatter(const int* __restrict__ src,
                                                 const int* __restrict__ dst,
                                                 const int* __restrict__ dbase,
                                                 const int* __restrict__ sbase,
                                                 const int* __restrict__ offd,
                                                 const int* __restrict__ offs,
                                                 unsigned* __restrict__ pairs,
                                                 unsigned char* __restrict__ srcb) {
    __shared__ int cd[NBUCK], cs[NBUCK];
    int tid = threadIdx.x, blk = blockIdx.x;
    for (int b = tid; b < NBUCK; b += 256) {
        cd[b] = dbase[b] + offd[blk * NBUCK + b];
        cs[b] = sbase[b] + offs[blk * NBUCK + b];
    }
    __syncthreads();
    int e0 = blk * CHUNK, e1 = min(E, e0 + CHUNK);
    for (int e = e0 + tid; e < e1; e += 256) {
        int s = src[e], d = dst[e];
        int pd = atomicAdd(&cd[d >> 7], 1);
        pairs[pd] = (unsigned)s | ((unsigned)(d & 127) << 20);
        int ps = atomicAdd(&cs[s >> 7], 1);
        srcb[ps] = (unsigned char)(s & 127);
    }
}

// ---- pass 4: per-bucket degrees/norms/rp/col (LDS only) ----
__global__ __launch_bounds__(256) void k_build(const unsigned* __restrict__ pairs,
                                               const unsigned char* __restrict__ srcb,
                                               const int* __restrict__ dbase,
                                               const int* __restrict__ sbase,
                                               int* __restrict__ rp,
                                               float* __restrict__ norm_d,
                                               float* __restrict__ norm_s,
                                               int* __restrict__ col) {
    __shared__ int cnt[128], scn[128], lcur[128];
    int b = blockIdx.x, tid = threadIdx.x, node0 = b << 7;
    int nmax = min(128, N - node0);
    if (tid < 128) cnt[tid] = 0;
    __syncthreads();
    int sb = sbase[b], se = sbase[b + 1];
    for (int e = sb + tid; e < se; e += 256) atomicAdd(&cnt[srcb[e]], 1);
    __syncthreads();
    if (tid < nmax) norm_s[node0 + tid] = rsqrtf(fmaxf((float)cnt[tid], 1.0f));
    __syncthreads();
    if (tid < 128) cnt[tid] = 0;
    __syncthreads();
    int beg = dbase[b], end = dbase[b + 1];
    for (int e = beg + tid; e < end; e += 256) atomicAdd(&cnt[pairs[e] >> 20], 1);
    __syncthreads();
    if (tid < 128) scn[tid] = cnt[tid];
    __syncthreads();
    for (int o = 1; o < 128; o <<= 1) {
        int t = (tid < 128 && tid >= o) ? scn[tid - o] : 0;
        __syncthreads();
        if (tid < 128) scn[tid] += t;
        __syncthreads();
    }
    if (tid < nmax) {
        int excl = beg + scn[tid] - cnt[tid];
        rp[node0 + tid] = excl;
        lcur[tid] = excl;
        norm_d[node0 + tid] = rsqrtf(fmaxf((float)cnt[tid], 1.0f));
    }
    if (b == 0 && tid == 0) rp[N] = E;
    __syncthreads();
    for (int e = beg + tid; e < end; e += 256) {
        unsigned p = pairs[e];
        int pos = atomicAdd(&lcur[p >> 20], 1);
        col[pos] = (int)(p & 0xFFFFFu);
    }
}

// ---- edge-balanced wave partition: wsrt[w] = first node of wave w ----
__global__ __launch_bounds__(256) void k_wpart(const int* __restrict__ rp,
                                               int* __restrict__ wsrt) {
    int w = blockIdx.x * 256 + threadIdx.x;
    if (w > NWAVE) return;
    if (w == 0) { wsrt[0] = 0; return; }
    if (w == NWAVE) { wsrt[NWAVE] = N; return; }
    int t = (int)((long long)w * E / NWAVE);
    int lo = 0, hi = N;
    while (lo < hi) { int mid = (lo + hi) >> 1; if (rp[mid] >= t) hi = mid; else lo = mid + 1; }
    wsrt[w] = lo;
}

// ---- W prep: Wt[n][k] = bf16(a[k]*W[k][n]) (transposed), cvec[n] = sum_k c[k]*W[k][n] ----
template <bool AFFINE>
__global__ __launch_bounds__(64) void k_wprep(const float* __restrict__ W,
                                              const float* __restrict__ ab,
                                              int fout,
                                              unsigned short* __restrict__ Wt,
                                              float* __restrict__ cvec) {
    int n = blockIdx.x, k = threadIdx.x;
    float w0 = W[k * fout + n], w1 = W[(k + 64) * fout + n];
    float a0 = AFFINE ? ab[k] : 1.0f;
    float a1 = AFFINE ? ab[k + 64] : 1.0f;
    Wt[n * 128 + k] = bfbits(a0 * w0);
    Wt[n * 128 + k + 64] = bfbits(a1 * w1);
    float cv = AFFINE ? (ab[128 + k] * w0 + ab[192 + k] * w1) : 0.0f;
    for (int o = 32; o; o >>= 1) cv += __shfl_xor(cv, o);
    if (k == 0) cvec[n] = cv;
}

// ---- MFMA GEMM: T = ns .* (Xbf16 @ Wt^T + cvec) ; 128 rows x FOUT per block ----
template <typename TIn, int FOUT>
__global__ __launch_bounds__(256) void k_gemm(const TIn* __restrict__ in,
                                              const unsigned short* __restrict__ Wt,
                                              const float* __restrict__ cvec,
                                              const float* __restrict__ ns,
                                              unsigned short* __restrict__ out) {
    constexpr int PK = 72;  // 64 + 8 pad: 2-way LDS conflict (free) on frag reads
    __shared__ __align__(16) unsigned short Xs[128 * PK];
    __shared__ __align__(16) unsigned short Wsh[FOUT * PK];
    const int tid = threadIdx.x;
    const int r0 = blockIdx.x * 128;
    const int wave = tid >> 6, lane = tid & 63;
    const int l16 = lane & 15, quad = lane >> 4;
    constexpr int MT = (FOUT == 128) ? 4 : 2;
    constexpr int NT = 4;
    const int wm = (FOUT == 128) ? (wave >> 1) : wave;
    const int wn = (FOUT == 128) ? (wave & 1) : 0;
    const int mbase = wm * (MT * 16);
    const int nbase = wn * 64;

    float4v acc[MT][NT];
#pragma unroll
    for (int mt = 0; mt < MT; ++mt)
#pragma unroll
        for (int nt = 0; nt < NT; ++nt) acc[mt][nt] = (float4v){0.f, 0.f, 0.f, 0.f};

    for (int kb = 0; kb < 128; kb += 64) {
        __syncthreads();
        for (int i = tid; i < 128 * 8; i += 256) {
            int row = i >> 3, j = i & 7;
            int grow = r0 + row;
            if constexpr (sizeof(TIn) == 4) {
                short8 p = {0, 0, 0, 0, 0, 0, 0, 0};
                if (grow < N) {
                    const float* g = (const float*)in + (size_t)grow * 128 + kb + j * 8;
                    float4 f0 = *(const float4*)g;
                    float4 f1 = *(const float4*)(g + 4);
                    p[0] = (short)bfbits(f0.x); p[1] = (short)bfbits(f0.y);
                    p[2] = (short)bfbits(f0.z); p[3] = (short)bfbits(f0.w);
                    p[4] = (short)bfbits(f1.x); p[5] = (short)bfbits(f1.y);
                    p[6] = (short)bfbits(f1.z); p[7] = (short)bfbits(f1.w);
                }
                *(short8*)&Xs[row * PK + j * 8] = p;
            } else {
                uint4 v = make_uint4(0, 0, 0, 0);
                if (grow < N)
                    v = *(const uint4*)((const unsigned short*)in + (size_t)grow * 128 + kb + j * 8);
                *(uint4*)&Xs[row * PK + j * 8] = v;
            }
        }
        for (int i = tid; i < FOUT * 8; i += 256) {
            int n = i >> 3, j = i & 7;
            uint4 v = *(const uint4*)&Wt[n * 128 + kb + j * 8];
            *(uint4*)&Wsh[n * PK + j * 8] = v;
        }
        __syncthreads();
#pragma unroll
        for (int ks = 0; ks < 64; ks += 32) {
            short8 af[MT], bfr[NT];
#pragma unroll
            for (int mt = 0; mt < MT; ++mt)
                af[mt] = *(const short8*)&Xs[(mbase + mt * 16 + l16) * PK + ks + quad * 8];
#pragma unroll
            for (int nt = 0; nt < NT; ++nt)
                bfr[nt] = *(const short8*)&Wsh[(nbase + nt * 16 + l16) * PK + ks + quad * 8];
#pragma unroll
            for (int mt = 0; mt < MT; ++mt)
#pragma unroll
                for (int nt = 0; nt < NT; ++nt)
                    acc[mt][nt] = __builtin_amdgcn_mfma_f32_16x16x32_bf16(
                        af[mt], bfr[nt], acc[mt][nt], 0, 0, 0);
        }
    }
    float cv[NT];
#pragma unroll
    for (int nt = 0; nt < NT; ++nt) cv[nt] = cvec[nbase + nt * 16 + l16];
#pragma unroll
    for (int mt = 0; mt < MT; ++mt) {
#pragma unroll
        for (int r = 0; r < 4; ++r) {
            int row = r0 + mbase + mt * 16 + quad * 4 + r;
            if (row < N) {
                float s = ns[row];
#pragma unroll
                for (int nt = 0; nt < NT; ++nt)
                    out[(size_t)row * FOUT + nbase + nt * 16 + l16] =
                        bfbits((acc[mt][nt][r] + cv[nt]) * s);
            }
        }
    }
}

// ------- fused aggregation (128 feats), uint2 loads: 2 edges per vmem instr -------
// lane: le = lane>>5 (edge select), lu = lane&31 (uint2 index -> feats 4lu..4lu+3)
__global__ __launch_bounds__(256) void k_agg128f(const uint2* __restrict__ T2, // N x 32 uint2
                                                 const int* __restrict__ wsrt,
                                                 const int* __restrict__ rp,
                                                 const int* __restrict__ col,
                                                 const float* __restrict__ norm_d,
                                                 const float* __restrict__ bias,
                                                 uint2* __restrict__ Hu,      // N x 32 uint2
                                                 float* __restrict__ part) {
    int tid = threadIdx.x, wave = tid >> 6, lane = tid & 63;
    int le = lane >> 5, lu = lane & 31;
    int w = blockIdx.x * 4 + wave;
    int n0 = wsrt[w], n1 = wsrt[w + 1];
    float bb0 = bias[4 * lu], bb1 = bias[4 * lu + 1];
    float bb2 = bias[4 * lu + 2], bb3 = bias[4 * lu + 3];
    float s0 = 0.f, q0 = 0.f, s1 = 0.f, q1 = 0.f;
    float s2 = 0.f, q2 = 0.f, s3 = 0.f, q3 = 0.f;
    for (int n = n0; n < n1; ++n) {
        int beg = rp[n], end = rp[n + 1];
        float a0 = 0.f, a1 = 0.f, a2 = 0.f, a3 = 0.f;
        int e = beg;
        for (; e + 16 <= end; e += 16) {
            uint2 v[8];
#pragma unroll
            for (int i = 0; i < 8; ++i) {
                int cA = col[e + 2 * i], cB = col[e + 2 * i + 1];
                int c = le ? cB : cA;
                v[i] = T2[(size_t)c * 32 + lu];
            }
#pragma unroll
            for (int i = 0; i < 8; ++i) {
                a0 += bflo(v[i].x); a1 += bfhi(v[i].x);
                a2 += bflo(v[i].y); a3 += bfhi(v[i].y);
            }
        }
        for (; e + 2 <= end; e += 2) {
            int cA = col[e], cB = col[e + 1];
            int c = le ? cB : cA;
            uint2 v = T2[(size_t)c * 32 + lu];
            a0 += bflo(v.x); a1 += bfhi(v.x);
            a2 += bflo(v.y); a3 += bfhi(v.y);
        }
        if (e < end && le == 0) {
            uint2 v = T2[(size_t)col[e] * 32 + lu];
            a0 += bflo(v.x); a1 += bfhi(v.x);
            a2 += bflo(v.y); a3 += bfhi(v.y);
        }
        a0 += __shfl_xor(a0, 32); a1 += __shfl_xor(a1, 32);
        a2 += __shfl_xor(a2, 32); a3 += __shfl_xor(a3, 32);
        float nd = norm_d[n];
        float r0 = fmaxf(a0 * nd + bb0, 0.f), r1 = fmaxf(a1 * nd + bb1, 0.f);
        float r2 = fmaxf(a2 * nd + bb2, 0.f), r3 = fmaxf(a3 * nd + bb3, 0.f);
        if (le == 0) {
            uint2 hv;
            hv.x = ((unsigned)bfbits(r1) << 16) | bfbits(r0);
            hv.y = ((unsigned)bfbits(r3) << 16) | bfbits(r2);
            Hu[(size_t)n * 32 + lu] = hv;
        }
        s0 += r0; q0 += r0 * r0; s1 += r1; q1 += r1 * r1;
        s2 += r2; q2 += r2 * r2; s3 += r3; q3 += r3 * r3;
    }
    __shared__ float red[4][32][8];
    if (le == 0) {
        red[wave][lu][0] = s0; red[wave][lu][1] = q0;
        red[wave][lu][2] = s1; red[wave][lu][3] = q1;
        red[wave][lu][4] = s2; red[wave][lu][5] = q2;
        red[wave][lu][6] = s3; red[wave][lu][7] = q3;
    }
    __syncthreads();
    float t = red[0][tid >> 3][tid & 7] + red[1][tid >> 3][tid & 7]
            + red[2][tid >> 3][tid & 7] + red[3][tid >> 3][tid & 7];
    part[blockIdx.x * 256 + tid] = t;
}

// hierarchical BN partial reduce: 2048 rows -> 64 rows
__global__ __launch_bounds__(256) void k_bnred(const float* __restrict__ part,
                                               float* __restrict__ part2) {
    int b = blockIdx.x, tid = threadIdx.x;
    float s = 0.f;
    for (int i = 0; i < AGG_BLOCKS / 64; ++i)
        s += part[(b * (AGG_BLOCKS / 64) + i) * 256 + tid];
    part2[b * 256 + tid] = s;
}

// reduce 64 partial rows -> folded affine (a|c). feat f: lu=f>>2, c=f&3
__global__ __launch_bounds__(128) void k_bnfin(const float* __restrict__ part2,
                                               const float* __restrict__ gamma,
                                               const float* __restrict__ beta,
                                               float* __restrict__ ab) {
    int f = threadIdx.x;
    int lu = f >> 2, c = f & 3;
    float s = 0.f, q = 0.f;
    for (int b = 0; b < 64; ++b) {
        s += part2[b * 256 + lu * 8 + c * 2];
        q += part2[b * 256 + lu * 8 + c * 2 + 1];
    }
    float mu = s * (1.0f / N);
    float var = q * (1.0f / N) - mu * mu;
    float aa = gamma[f] * rsqrtf(var + BN_EPS);
    ab[f] = aa;
    ab[128 + f] = beta[f] - mu * aa;
}

// ------- fused aggregation (64 feats), uint2 loads: 4 edges per vmem instr + log_softmax -------
// lane: le = lane>>4 (edge select 0..3), lu = lane&15 (uint2 -> feats 4lu..4lu+3)
__global__ __launch_bounds__(256) void k_agg64f(const uint2* __restrict__ T2, // N x 16 uint2
                                                const int* __restrict__ wsrt,
                                                const int* __restrict__ rp,
                                                const int* __restrict__ col,
                                                const float* __restrict__ norm_d,
                                                const float* __restrict__ b3,
                                                float* __restrict__ out) {
    int wave = threadIdx.x >> 6, lane = threadIdx.x & 63;
    int le = lane >> 4, lu = lane & 15;
    int w = blockIdx.x * 4 + wave;
    int n0 = wsrt[w], n1 = wsrt[w + 1];
    float bb0 = b3[4 * lu], bb1 = b3[4 * lu + 1];
    float bb2 = b3[4 * lu + 2], bb3 = b3[4 * lu + 3];
    for (int n = n0; n < n1; ++n) {
        int beg = rp[n], end = rp[n + 1];
        float a0 = 0.f, a1 = 0.f, a2 = 0.f, a3 = 0.f;
        int e = beg;
        for (; e + 32 <= end; e += 32) {
            uint2 v[8];
#pragma unroll
            for (int i = 0; i < 8; ++i) {
                int cA = col[e + 4 * i], cB = col[e + 4 * i + 1];
                int cC = col[e + 4 * i + 2], cD = col[e + 4 * i + 3];
                int c01 = (le & 1) ? cB : cA;
                int c23 = (le & 1) ? cD : cC;
                int c = (le & 2) ? c23 : c01;
                v[i] = T2[(size_t)c * 16 + lu];
            }
#pragma unroll
            for (int i = 0; i < 8; ++i) {
                a0 += bflo(v[i].x); a1 += bfhi(v[i].x);
                a2 += bflo(v[i].y); a3 += bfhi(v[i].y);
            }
        }
        for (; e + 4 <= end; e += 4) {
            int cA = col[e], cB = col[e + 1], cC = col[e + 2], cD = col[e + 3];
            int c01 = (le & 1) ? cB : cA;
            int c23 = (le & 1) ? cD : cC;
            int c = (le & 2) ? c23 : c01;
            uint2 v = T2[(size_t)c * 16 + lu];
            a0 += bflo(v.x); a1 += bfhi(v.x);
            a2 += bflo(v.y); a3 += bfhi(v.y);
        }
        if (e + le < end) {
            uint2 v = T2[(size_t)col[e + le] * 16 + lu];
            a0 += bflo(v.x); a1 += bfhi(v.x);
            a2 += bflo(v.y); a3 += bfhi(v.y);
        }
        a0 += __shfl_xor(a0, 16); a1 += __shfl_xor(a1, 16);
        a2 += __shfl_xor(a2, 16); a3 += __shfl_xor(a3, 16);
        a0 += __shfl_xor(a0, 32); a1 += __shfl_xor(a1, 32);
        a2 += __shfl_xor(a2, 32); a3 += __shfl_xor(a3, 32);
        float nd = norm_d[n];
        float z0 = a0 * nd + bb0, z1 = a1 * nd + bb1;
        float z2 = a2 * nd + bb2, z3 = a3 * nd + bb3;
        float m = fmaxf(fmaxf(z0, z1), fmaxf(z2, z3));
        m = fmaxf(m, __shfl_xor(m, 1));
        m = fmaxf(m, __shfl_xor(m, 2));
        m = fmaxf(m, __shfl_xor(m, 4));
        m = fmaxf(m, __shfl_xor(m, 8));
        float ex = __expf(z0 - m) + __expf(z1 - m) + __expf(z2 - m) + __expf(z3 - m);
        ex += __shfl_xor(ex, 1);
        ex += __shfl_xor(ex, 2);
        ex += __shfl_xor(ex, 4);
        ex += __shfl_xor(ex, 8);
        float l = m + __logf(ex);
        if (le == 0) {
            float4 o4 = make_float4(z0 - l, z1 - l, z2 - l, z3 - l);
            *(float4*)&out[(size_t)n * 64 + lu * 4] = o4;
        }
    }
}

extern "C" void kernel_launch(void* const* d_in, const int* in_sizes, int n_in,
                              void* d_out, int out_size, void* d_ws, size_t ws_size,
                              hipStream_t stream) {
    const float* x  = (const float*)d_in[0];
    const int* src  = (const int*)d_in[1];
    const int* dst  = (const int*)d_in[2];
    const float* W1 = (const float*)d_in[3];
    const float* b1 = (const float*)d_in[4];
    const float* W2 = (const float*)d_in[5];
    const float* b2 = (const float*)d_in[6];
    const float* W3 = (const float*)d_in[7];
    const float* b3 = (const float*)d_in[8];
    const float* g1 = (const float*)d_in[9];
    const float* be1= (const float*)d_in[10];
    const float* g2 = (const float*)d_in[11];
    const float* be2= (const float*)d_in[12];
    float* out = (float*)d_out;

    char* ws = (char*)d_ws;
    int* tot_d = (int*)(ws + OFF_TOT_D);
    int* tot_s = (int*)(ws + OFF_TOT_S);
    int* dbase = (int*)(ws + OFF_DBASE);
    int* sbase = (int*)(ws + OFF_SBASE);
    float* ab1 = (float*)(ws + OFF_AB1);
    float* ab2 = (float*)(ws + OFF_AB2);
    float* cvec = (float*)(ws + OFF_CVEC);
    unsigned short* Wt = (unsigned short*)(ws + OFF_WT);
    int* wsrt = (int*)(ws + OFF_WSRT);
    float* bnp2 = (float*)(ws + OFF_BNP2);
    float* bnp = (float*)(ws + OFF_BNP);
    float* norm_s = (float*)(ws + OFF_NORM_S);
    float* norm_d = (float*)(ws + OFF_NORM_D);
    int* rp = (int*)(ws + OFF_RP);
    int* cnt_d = (int*)(ws + OFF_CNT_D);
    int* cnt_s = (int*)(ws + OFF_CNT_S);
    int* offd = (int*)(ws + OFF_OFFD);
    int* offs = (int*)(ws + OFF_OFFS);
    int* col = (int*)(ws + OFF_COL);
    unsigned char* srcb = (unsigned char*)(ws + OFF_SRCB);
    unsigned* pairs = (unsigned*)(ws + OFF_PAIRS);
    unsigned short* H = (unsigned short*)(ws + OFF_H);
    unsigned short* T = (unsigned short*)(ws + OFF_T);

    // CSR build — zero global atomics
    k_count<<<NBLK, 256, 0, stream>>>(src, dst, cnt_s, cnt_d);
    k_scanA<<<NBUCK, 256, 0, stream>>>(cnt_d, offd, tot_d);
    k_scanA<<<NBUCK, 256, 0, stream>>>(cnt_s, offs, tot_s);
    k_scanB<<<1, 1024, 0, stream>>>(tot_d, tot_s, dbase, sbase);
    k_scatter<<<NBLK, 256, 0, stream>>>(src, dst, dbase, sbase, offd, offs, pairs, srcb);
    k_build<<<NBUCK, 256, 0, stream>>>(pairs, srcb, dbase, sbase, rp, norm_d, norm_s, col);
    k_wpart<<<(NWAVE + 256) / 256, 256, 0, stream>>>(rp, wsrt);

    const int gemm_grid = (N + 127) / 128;

    // Layer 1
    k_wprep<false><<<128, 64, 0, stream>>>(W1, nullptr, 128, Wt, cvec);
    k_gemm<float, 128><<<gemm_grid, 256, 0, stream>>>(x, Wt, cvec, norm_s, T);
    k_agg128f<<<AGG_BLOCKS, 256, 0, stream>>>((const uint2*)T, wsrt, rp, col, norm_d, b1, (uint2*)H, bnp);
    k_bnred<<<64, 256, 0, stream>>>(bnp, bnp2);
    k_bnfin<<<1, 128, 0, stream>>>(bnp2, g1, be1, ab1);

    // Layer 2
    k_wprep<true><<<128, 64, 0, stream>>>(W2, ab1, 128, Wt, cvec);
    k_gemm<__hip_bfloat16, 128><<<gemm_grid, 256, 0, stream>>>((const __hip_bfloat16*)H, Wt, cvec, norm_s, T);
    k_agg128f<<<AGG_BLOCKS, 256, 0, stream>>>((const uint2*)T, wsrt, rp, col, norm_d, b2, (uint2*)H, bnp);
    k_bnred<<<64, 256, 0, stream>>>(bnp, bnp2);
    k_bnfin<<<1, 128, 0, stream>>>(bnp2, g2, be2, ab2);

    // Layer 3 (64 outputs) + log_softmax
    k_wprep<true><<<64, 64, 0, stream>>>(W3, ab2, 64, Wt, cvec);
    k_gemm<__hip_bfloat16, 64><<<gemm_grid, 256, 0, stream>>>((const __hip_bfloat16*)H, Wt, cvec, norm_s, T);
    k_agg64f<<<AGG_BLOCKS, 256, 0, stream>>>((const uint2*)T, wsrt, rp, col, norm_d, b3, out);
}

// Round 9
// 646.530 us; speedup vs baseline: 1.6218x; 1.1199x over previous
//
#include <hip/hip_runtime.h>
#include <hip/hip_bf16.h>
#include <cstdint>

// Problem constants (fixed by the reference).
static constexpr int N = 100000;
static constexpr int E = 3200000;
static constexpr float BN_EPS = 1e-5f;
static constexpr int NBUCK = (N + 127) >> 7;   // 782 buckets of 128 nodes
static constexpr int NBLK = 256;               // edge-counting blocks
static constexpr int CHUNK = E / NBLK;         // 12500 edges per block (exact)
static constexpr int AGG_BLOCKS = 2048;        // 8192 waves = 100% occupancy cap
static constexpr int NWAVE = AGG_BLOCKS * 4;   // edge-balanced wave partitions

// ---------------- workspace layout (no zero-init required anywhere) ----------------
static constexpr size_t OFF_TOT_D = 0;              // NBUCK int
static constexpr size_t OFF_TOT_S = 3328;           // NBUCK int
static constexpr size_t OFF_DBASE = 6656;           // NBUCK+1 int
static constexpr size_t OFF_SBASE = 9984;           // NBUCK+1 int
static constexpr size_t OFF_CVEC  = 15360;          // 128 f32
static constexpr size_t OFF_WT    = 16384;          // 128*128 bf16 (transposed, affine-folded W)
static constexpr size_t OFF_WSRT  = 49152;          // NWAVE+1 int (balanced wave starts)
static constexpr size_t OFF_BNP2  = 82944;          // 64*256 f32
static constexpr size_t OFF_BNP   = 148480;         // AGG_BLOCKS*256 f32 = 2 MB
static constexpr size_t OFF_NORM_S= 2245632;        // N f32
static constexpr size_t OFF_NORM_D= 2645632;        // N f32
static constexpr size_t OFF_RP    = 3045632;        // N+1 int
static constexpr size_t OFF_CNT_D = 3445760;        // NBLK*NBUCK int
static constexpr size_t OFF_CNT_S = 4246528;        // NBLK*NBUCK int
static constexpr size_t OFF_OFFD  = 5047296;        // NBLK*NBUCK int
static constexpr size_t OFF_OFFS  = 5848064;        // NBLK*NBUCK int
static constexpr size_t OFF_COL   = 6648832;        // E int
static constexpr size_t OFF_SRCB  = 19448832;       // E uchar
static constexpr size_t OFF_PAIRS = 22648832;       // E uint (s | dloc<<20)
static constexpr size_t OFF_H     = 35448832;       // N*128 bf16
static constexpr size_t OFF_T     = 61048832;       // N*128 bf16

using short8  = __attribute__((ext_vector_type(8))) short;
using float4v = __attribute__((ext_vector_type(4))) float;

__device__ inline float bflo(unsigned v) { return __uint_as_float(v << 16); }
__device__ inline float bfhi(unsigned v) { return __uint_as_float(v & 0xffff0000u); }
__device__ inline unsigned short bfbits(float x) {
    __hip_bfloat16 h = __float2bfloat16(x);
    return *reinterpret_cast<unsigned short*>(&h);
}

// ---- pass 1: per-block privatized bucket histograms (LDS atomics only) ----
__global__ __launch_bounds__(256) void k_count(const int* __restrict__ src,
                                               const int* __restrict__ dst,
                                               int* __restrict__ cnt_s,
                                               int* __restrict__ cnt_d) {
    __shared__ int hs[NBUCK], hd[NBUCK];
    int tid = threadIdx.x, blk = blockIdx.x;
    for (int b = tid; b < NBUCK; b += 256) { hs[b] = 0; hd[b] = 0; }
    __syncthreads();
    int e0 = blk * CHUNK, e1 = min(E, e0 + CHUNK);
    for (int e = e0 + tid; e < e1; e += 256) {
        atomicAdd(&hs[src[e] >> 7], 1);
        atomicAdd(&hd[dst[e] >> 7], 1);
    }
    __syncthreads();
    for (int b = tid; b < NBUCK; b += 256) {
        cnt_s[blk * NBUCK + b] = hs[b];
        cnt_d[blk * NBUCK + b] = hd[b];
    }
}

// ---- pass 2a: per-bucket scan over the 256 counting blocks (d and s in one grid) ----
__global__ __launch_bounds__(256) void k_scanA2(const int* __restrict__ cnt_d,
                                                const int* __restrict__ cnt_s,
                                                int* __restrict__ offd,
                                                int* __restrict__ offs,
                                                int* __restrict__ tot_d,
                                                int* __restrict__ tot_s) {
    __shared__ int sd[256];
    int which = (blockIdx.x >= NBUCK) ? 1 : 0;
    int b = blockIdx.x - which * NBUCK;
    const int* cnt = which ? cnt_s : cnt_d;
    int* off = which ? offs : offd;
    int* tot = which ? tot_s : tot_d;
    int tid = threadIdx.x;
    int v = cnt[tid * NBUCK + b];
    sd[tid] = v;
    __syncthreads();
    for (int o = 1; o < 256; o <<= 1) {
        int t = (tid >= o) ? sd[tid - o] : 0;
        __syncthreads();
        sd[tid] += t;
        __syncthreads();
    }
    off[tid * NBUCK + b] = sd[tid] - v;
    if (tid == 255) tot[b] = sd[255];
}

// ---- pass 2b: scan bucket totals -> bases ----
__global__ __launch_bounds__(1024) void k_scanB(const int* __restrict__ tot_d,
                                                const int* __restrict__ tot_s,
                                                int* __restrict__ dbase,
                                                int* __restrict__ sbase) {
    __shared__ int sd[1024], ss[1024];
    int tid = threadIdx.x;
    int vd = (tid < NBUCK) ? tot_d[tid] : 0;
    int vs = (tid < NBUCK) ? tot_s[tid] : 0;
    sd[tid] = vd; ss[tid] = vs;
    __syncthreads();
    for (int o = 1; o < 1024; o <<= 1) {
        int td = (tid >= o) ? sd[tid - o] : 0;
        int ts = (tid >= o) ? ss[tid - o] : 0;
        __syncthreads();
        sd[tid] += td; ss[tid] += ts;
        __syncthreads();
    }
    if (tid < NBUCK) { dbase[tid] = sd[tid] - vd; sbase[tid] = ss[tid] - vs; }
    if (tid == 0) { dbase[NBUCK] = E; sbase[NBUCK] = E; }
}

// ---- pass 3: deterministic-offset scatter (LDS cursors, zero global atomics) ----
__global__ __launch_bounds__(256) void k_scatter(const int* __restrict__ src,
                                                 const int* __restrict__ dst,
                                                 const int* __restrict__ dbase,
                                                 const int* __restrict__ sbase,
                                                 const int* __restrict__ offd,
                                                 const int* __restrict__ offs,
                                                 unsigned* __restrict__ pairs,
                                                 unsigned char* __restrict__ srcb) {
    __shared__ int cd[NBUCK], cs[NBUCK];
    int tid = threadIdx.x, blk = blockIdx.x;
    for (int b = tid; b < NBUCK; b += 256) {
        cd[b] = dbase[b] + offd[blk * NBUCK + b];
        cs[b] = sbase[b] + offs[blk * NBUCK + b];
    }
    __syncthreads();
    int e0 = blk * CHUNK, e1 = min(E, e0 + CHUNK);
    for (int e = e0 + tid; e < e1; e += 256) {
        int s = src[e], d = dst[e];
        int pd = atomicAdd(&cd[d >> 7], 1);
        pairs[pd] = (unsigned)s | ((unsigned)(d & 127) << 20);
        int ps = atomicAdd(&cs[s >> 7], 1);
        srcb[ps] = (unsigned char)(s & 127);
    }
}

// ---- pass 4: per-bucket degrees/norms/rp/col (LDS only) ----
__global__ __launch_bounds__(256) void k_build(const unsigned* __restrict__ pairs,
                                               const unsigned char* __restrict__ srcb,
                                               const int* __restrict__ dbase,
                                               const int* __restrict__ sbase,
                                               int* __restrict__ rp,
                                               float* __restrict__ norm_d,
                                               float* __restrict__ norm_s,
                                               int* __restrict__ col) {
    __shared__ int cnt[128], scn[128], lcur[128];
    int b = blockIdx.x, tid = threadIdx.x, node0 = b << 7;
    int nmax = min(128, N - node0);
    if (tid < 128) cnt[tid] = 0;
    __syncthreads();
    int sb = sbase[b], se = sbase[b + 1];
    for (int e = sb + tid; e < se; e += 256) atomicAdd(&cnt[srcb[e]], 1);
    __syncthreads();
    if (tid < nmax) norm_s[node0 + tid] = rsqrtf(fmaxf((float)cnt[tid], 1.0f));
    __syncthreads();
    if (tid < 128) cnt[tid] = 0;
    __syncthreads();
    int beg = dbase[b], end = dbase[b + 1];
    for (int e = beg + tid; e < end; e += 256) atomicAdd(&cnt[pairs[e] >> 20], 1);
    __syncthreads();
    if (tid < 128) scn[tid] = cnt[tid];
    __syncthreads();
    for (int o = 1; o < 128; o <<= 1) {
        int t = (tid < 128 && tid >= o) ? scn[tid - o] : 0;
        __syncthreads();
        if (tid < 128) scn[tid] += t;
        __syncthreads();
    }
    if (tid < nmax) {
        int excl = beg + scn[tid] - cnt[tid];
        rp[node0 + tid] = excl;
        lcur[tid] = excl;
        norm_d[node0 + tid] = rsqrtf(fmaxf((float)cnt[tid], 1.0f));
    }
    if (b == 0 && tid == 0) rp[N] = E;
    __syncthreads();
    for (int e = beg + tid; e < end; e += 256) {
        unsigned p = pairs[e];
        int pos = atomicAdd(&lcur[p >> 20], 1);
        col[pos] = (int)(p & 0xFFFFFu);
    }
}

// ---- edge-balanced wave partition: wsrt[w] = first node of wave w ----
__global__ __launch_bounds__(256) void k_wpart(const int* __restrict__ rp,
                                               int* __restrict__ wsrt) {
    int w = blockIdx.x * 256 + threadIdx.x;
    if (w > NWAVE) return;
    if (w == 0) { wsrt[0] = 0; return; }
    if (w == NWAVE) { wsrt[NWAVE] = N; return; }
    int t = (int)((long long)w * E / NWAVE);
    int lo = 0, hi = N;
    while (lo < hi) { int mid = (lo + hi) >> 1; if (rp[mid] >= t) hi = mid; else lo = mid + 1; }
    wsrt[w] = lo;
}

// ---- W prep (fused BN finalize): computes per-feature a,c from BN partials, then
//      Wt[n][k] = bf16(a[k]*W[k][n]) (transposed), cvec[n] = sum_k c[k]*W[k][n] ----
template <bool AFFINE>
__global__ __launch_bounds__(64) void k_wprep(const float* __restrict__ W,
                                              const float* __restrict__ part2, // 64 x 256
                                              const float* __restrict__ gamma,
                                              const float* __restrict__ beta,
                                              int fout,
                                              unsigned short* __restrict__ Wt,
                                              float* __restrict__ cvec) {
    int n = blockIdx.x, k = threadIdx.x;
    float a0 = 1.f, c0 = 0.f, a1 = 1.f, c1 = 0.f;
    if (AFFINE) {
        // feature f: sum at (f&1?128:0)+(f>>1), sumsq at (f&1?192:64)+(f>>1)
        int l0 = ((k & 1) ? 128 : 0) + (k >> 1);
        int m0 = ((k & 1) ? 192 : 64) + (k >> 1);
        int l1 = l0 + 32, m1 = m0 + 32;   // f+64: same parity, index+32
        float s0 = 0.f, q0 = 0.f, s1 = 0.f, q1 = 0.f;
        for (int b = 0; b < 64; ++b) {
            const float* r = part2 + b * 256;
            s0 += r[l0]; q0 += r[m0];
            s1 += r[l1]; q1 += r[m1];
        }
        float mu0 = s0 * (1.0f / N), var0 = q0 * (1.0f / N) - mu0 * mu0;
        a0 = gamma[k] * rsqrtf(var0 + BN_EPS);
        c0 = beta[k] - mu0 * a0;
        float mu1 = s1 * (1.0f / N), var1 = q1 * (1.0f / N) - mu1 * mu1;
        a1 = gamma[k + 64] * rsqrtf(var1 + BN_EPS);
        c1 = beta[k + 64] - mu1 * a1;
    }
    float w0 = W[k * fout + n], w1 = W[(k + 64) * fout + n];
    Wt[n * 128 + k] = bfbits(a0 * w0);
    Wt[n * 128 + k + 64] = bfbits(a1 * w1);
    float cv = c0 * w0 + c1 * w1;
    for (int o = 32; o; o >>= 1) cv += __shfl_xor(cv, o);
    if (k == 0) cvec[n] = cv;
}

// ---- MFMA GEMM: T = ns .* (Xbf16 @ Wt^T + cvec) ; 128 rows x FOUT per block ----
template <typename TIn, int FOUT>
__global__ __launch_bounds__(256) void k_gemm(const TIn* __restrict__ in,
                                              const unsigned short* __restrict__ Wt,
                                              const float* __restrict__ cvec,
                                              const float* __restrict__ ns,
                                              unsigned short* __restrict__ out) {
    constexpr int PK = 72;  // 64 + 8 pad: 2-way LDS conflict (free) on frag reads
    __shared__ __align__(16) unsigned short Xs[128 * PK];
    __shared__ __align__(16) unsigned short Wsh[FOUT * PK];
    const int tid = threadIdx.x;
    const int r0 = blockIdx.x * 128;
    const int wave = tid >> 6, lane = tid & 63;
    const int l16 = lane & 15, quad = lane >> 4;
    constexpr int MT = (FOUT == 128) ? 4 : 2;
    constexpr int NT = 4;
    const int wm = (FOUT == 128) ? (wave >> 1) : wave;
    const int wn = (FOUT == 128) ? (wave & 1) : 0;
    const int mbase = wm * (MT * 16);
    const int nbase = wn * 64;

    float4v acc[MT][NT];
#pragma unroll
    for (int mt = 0; mt < MT; ++mt)
#pragma unroll
        for (int nt = 0; nt < NT; ++nt) acc[mt][nt] = (float4v){0.f, 0.f, 0.f, 0.f};

    for (int kb = 0; kb < 128; kb += 64) {
        __syncthreads();
        for (int i = tid; i < 128 * 8; i += 256) {
            int row = i >> 3, j = i & 7;
            int grow = r0 + row;
            if constexpr (sizeof(TIn) == 4) {
                short8 p = {0, 0, 0, 0, 0, 0, 0, 0};
                if (grow < N) {
                    const float* g = (const float*)in + (size_t)grow * 128 + kb + j * 8;
                    float4 f0 = *(const float4*)g;
                    float4 f1 = *(const float4*)(g + 4);
                    p[0] = (short)bfbits(f0.x); p[1] = (short)bfbits(f0.y);
                    p[2] = (short)bfbits(f0.z); p[3] = (short)bfbits(f0.w);
                    p[4] = (short)bfbits(f1.x); p[5] = (short)bfbits(f1.y);
                    p[6] = (short)bfbits(f1.z); p[7] = (short)bfbits(f1.w);
                }
                *(short8*)&Xs[row * PK + j * 8] = p;
            } else {
                uint4 v = make_uint4(0, 0, 0, 0);
                if (grow < N)
                    v = *(const uint4*)((const unsigned short*)in + (size_t)grow * 128 + kb + j * 8);
                *(uint4*)&Xs[row * PK + j * 8] = v;
            }
        }
        for (int i = tid; i < FOUT * 8; i += 256) {
            int n = i >> 3, j = i & 7;
            uint4 v = *(const uint4*)&Wt[n * 128 + kb + j * 8];
            *(uint4*)&Wsh[n * PK + j * 8] = v;
        }
        __syncthreads();
#pragma unroll
        for (int ks = 0; ks < 64; ks += 32) {
            short8 af[MT], bfr[NT];
#pragma unroll
            for (int mt = 0; mt < MT; ++mt)
                af[mt] = *(const short8*)&Xs[(mbase + mt * 16 + l16) * PK + ks + quad * 8];
#pragma unroll
            for (int nt = 0; nt < NT; ++nt)
                bfr[nt] = *(const short8*)&Wsh[(nbase + nt * 16 + l16) * PK + ks + quad * 8];
#pragma unroll
            for (int mt = 0; mt < MT; ++mt)
#pragma unroll
                for (int nt = 0; nt < NT; ++nt)
                    acc[mt][nt] = __builtin_amdgcn_mfma_f32_16x16x32_bf16(
                        af[mt], bfr[nt], acc[mt][nt], 0, 0, 0);
        }
    }
    float cv[NT];
#pragma unroll
    for (int nt = 0; nt < NT; ++nt) cv[nt] = cvec[nbase + nt * 16 + l16];
#pragma unroll
    for (int mt = 0; mt < MT; ++mt) {
#pragma unroll
        for (int r = 0; r < 4; ++r) {
            int row = r0 + mbase + mt * 16 + quad * 4 + r;
            if (row < N) {
                float s = ns[row];
#pragma unroll
                for (int nt = 0; nt < NT; ++nt)
                    out[(size_t)row * FOUT + nbase + nt * 16 + l16] =
                        bfbits((acc[mt][nt][r] + cv[nt]) * s);
            }
        }
    }
}

// ------- fused aggregation (128 feats): lane = uint index, 16-deep gather pipeline -------
__global__ __launch_bounds__(256, 8) void k_agg128f(const unsigned* __restrict__ T2, // N x 64 uints
                                                    const int* __restrict__ wsrt,
                                                    const int* __restrict__ rp,
                                                    const int* __restrict__ col,
                                                    const float* __restrict__ norm_d,
                                                    const float* __restrict__ bias,
                                                    unsigned* __restrict__ Hu,      // N x 64 uints
                                                    float* __restrict__ part) {
    int tid = threadIdx.x, wave = tid >> 6, lane = tid & 63;
    int w = blockIdx.x * 4 + wave;
    int n0 = wsrt[w], n1 = wsrt[w + 1];
    float bb0 = bias[2 * lane], bb1 = bias[2 * lane + 1];
    float s0 = 0.f, q0 = 0.f, s1 = 0.f, q1 = 0.f;
    for (int n = n0; n < n1; ++n) {
        int beg = rp[n], end = rp[n + 1];
        float a0 = 0.0f, a1 = 0.0f;
        int e = beg;
        for (; e + 16 <= end; e += 16) {
            int c[16];
#pragma unroll
            for (int i = 0; i < 16; ++i) c[i] = col[e + i];
            unsigned v[16];
#pragma unroll
            for (int i = 0; i < 16; ++i) v[i] = T2[(size_t)c[i] * 64 + lane];
#pragma unroll
            for (int i = 0; i < 16; ++i) { a0 += bflo(v[i]); a1 += bfhi(v[i]); }
        }
        for (; e + 8 <= end; e += 8) {
            int c[8];
#pragma unroll
            for (int i = 0; i < 8; ++i) c[i] = col[e + i];
            unsigned v[8];
#pragma unroll
            for (int i = 0; i < 8; ++i) v[i] = T2[(size_t)c[i] * 64 + lane];
#pragma unroll
            for (int i = 0; i < 8; ++i) { a0 += bflo(v[i]); a1 += bfhi(v[i]); }
        }
        for (; e < end; ++e) {
            unsigned v = T2[(size_t)col[e] * 64 + lane];
            a0 += bflo(v); a1 += bfhi(v);
        }
        float nd = norm_d[n];
        float r0 = fmaxf(a0 * nd + bb0, 0.0f);
        float r1 = fmaxf(a1 * nd + bb1, 0.0f);
        Hu[(size_t)n * 64 + lane] = ((unsigned)bfbits(r1) << 16) | bfbits(r0);
        s0 += r0; q0 += r0 * r0; s1 += r1; q1 += r1 * r1;
    }
    __shared__ float red[4][256];
    red[wave][lane] = s0;
    red[wave][64 + lane] = q0;
    red[wave][128 + lane] = s1;
    red[wave][192 + lane] = q1;
    __syncthreads();
    float t = red[0][tid] + red[1][tid] + red[2][tid] + red[3][tid];
    part[blockIdx.x * 256 + tid] = t;
}

// hierarchical BN partial reduce: 2048 rows -> 64 rows
__global__ __launch_bounds__(256) void k_bnred(const float* __restrict__ part,
                                               float* __restrict__ part2) {
    int b = blockIdx.x, tid = threadIdx.x;
    float s = 0.f;
    for (int i = 0; i < AGG_BLOCKS / 64; ++i)
        s += part[(b * (AGG_BLOCKS / 64) + i) * 256 + tid];
    part2[b * 256 + tid] = s;
}

// ------- fused aggregation (64 feats): lane = feat, 16-deep pipeline + log_softmax -------
__global__ __launch_bounds__(256, 8) void k_agg64f(const __hip_bfloat16* __restrict__ T,
                                                   const int* __restrict__ wsrt,
                                                   const int* __restrict__ rp,
                                                   const int* __restrict__ col,
                                                   const float* __restrict__ norm_d,
                                                   const float* __restrict__ b3,
                                                   float* __restrict__ out) {
    int wave = threadIdx.x >> 6, lane = threadIdx.x & 63;
    int w = blockIdx.x * 4 + wave;
    int n0 = wsrt[w], n1 = wsrt[w + 1];
    float bb = b3[lane];
    for (int n = n0; n < n1; ++n) {
        int beg = rp[n], end = rp[n + 1];
        float a0 = 0.0f;
        int e = beg;
        for (; e + 16 <= end; e += 16) {
            int c[16];
#pragma unroll
            for (int i = 0; i < 16; ++i) c[i] = col[e + i];
            float v[16];
#pragma unroll
            for (int i = 0; i < 16; ++i) v[i] = __bfloat162float(T[(size_t)c[i] * 64 + lane]);
#pragma unroll
            for (int i = 0; i < 16; ++i) a0 += v[i];
        }
        for (; e + 8 <= end; e += 8) {
            int c[8];
#pragma unroll
            for (int i = 0; i < 8; ++i) c[i] = col[e + i];
            float v[8];
#pragma unroll
            for (int i = 0; i < 8; ++i) v[i] = __bfloat162float(T[(size_t)c[i] * 64 + lane]);
#pragma unroll
            for (int i = 0; i < 8; ++i) a0 += v[i];
        }
        for (; e < end; ++e) a0 += __bfloat162float(T[(size_t)col[e] * 64 + lane]);
        float z = a0 * norm_d[n] + bb;
        float m = z;
        for (int o = 32; o; o >>= 1) m = fmaxf(m, __shfl_xor(m, o));
        float ex = __expf(z - m);
        float ssum = ex;
        for (int o = 32; o; o >>= 1) ssum += __shfl_xor(ssum, o);
        out[(size_t)n * 64 + lane] = z - m - __logf(ssum);
    }
}

extern "C" void kernel_launch(void* const* d_in, const int* in_sizes, int n_in,
                              void* d_out, int out_size, void* d_ws, size_t ws_size,
                              hipStream_t stream) {
    const float* x  = (const float*)d_in[0];
    const int* src  = (const int*)d_in[1];
    const int* dst  = (const int*)d_in[2];
    const float* W1 = (const float*)d_in[3];
    const float* b1 = (const float*)d_in[4];
    const float* W2 = (const float*)d_in[5];
    const float* b2 = (const float*)d_in[6];
    const float* W3 = (const float*)d_in[7];
    const float* b3 = (const float*)d_in[8];
    const float* g1 = (const float*)d_in[9];
    const float* be1= (const float*)d_in[10];
    const float* g2 = (const float*)d_in[11];
    const float* be2= (const float*)d_in[12];
    float* out = (float*)d_out;

    char* ws = (char*)d_ws;
    int* tot_d = (int*)(ws + OFF_TOT_D);
    int* tot_s = (int*)(ws + OFF_TOT_S);
    int* dbase = (int*)(ws + OFF_DBASE);
    int* sbase = (int*)(ws + OFF_SBASE);
    float* cvec = (float*)(ws + OFF_CVEC);
    unsigned short* Wt = (unsigned short*)(ws + OFF_WT);
    int* wsrt = (int*)(ws + OFF_WSRT);
    float* bnp2 = (float*)(ws + OFF_BNP2);
    float* bnp = (float*)(ws + OFF_BNP);
    float* norm_s = (float*)(ws + OFF_NORM_S);
    float* norm_d = (float*)(ws + OFF_NORM_D);
    int* rp = (int*)(ws + OFF_RP);
    int* cnt_d = (int*)(ws + OFF_CNT_D);
    int* cnt_s = (int*)(ws + OFF_CNT_S);
    int* offd = (int*)(ws + OFF_OFFD);
    int* offs = (int*)(ws + OFF_OFFS);
    int* col = (int*)(ws + OFF_COL);
    unsigned char* srcb = (unsigned char*)(ws + OFF_SRCB);
    unsigned* pairs = (unsigned*)(ws + OFF_PAIRS);
    unsigned short* H = (unsigned short*)(ws + OFF_H);
    unsigned short* T = (unsigned short*)(ws + OFF_T);

    // CSR build — zero global atomics
    k_count<<<NBLK, 256, 0, stream>>>(src, dst, cnt_s, cnt_d);
    k_scanA2<<<2 * NBUCK, 256, 0, stream>>>(cnt_d, cnt_s, offd, offs, tot_d, tot_s);
    k_scanB<<<1, 1024, 0, stream>>>(tot_d, tot_s, dbase, sbase);
    k_scatter<<<NBLK, 256, 0, stream>>>(src, dst, dbase, sbase, offd, offs, pairs, srcb);
    k_build<<<NBUCK, 256, 0, stream>>>(pairs, srcb, dbase, sbase, rp, norm_d, norm_s, col);
    k_wpart<<<(NWAVE + 256) / 256, 256, 0, stream>>>(rp, wsrt);

    const int gemm_grid = (N + 127) / 128;

    // Layer 1
    k_wprep<false><<<128, 64, 0, stream>>>(W1, nullptr, nullptr, nullptr, 128, Wt, cvec);
    k_gemm<float, 128><<<gemm_grid, 256, 0, stream>>>(x, Wt, cvec, norm_s, T);
    k_agg128f<<<AGG_BLOCKS, 256, 0, stream>>>((const unsigned*)T, wsrt, rp, col, norm_d, b1, (unsigned*)H, bnp);
    k_bnred<<<64, 256, 0, stream>>>(bnp, bnp2);

    // Layer 2 (wprep fuses BN finalize from bnp2)
    k_wprep<true><<<128, 64, 0, stream>>>(W2, bnp2, g1, be1, 128, Wt, cvec);
    k_gemm<__hip_bfloat16, 128><<<gemm_grid, 256, 0, stream>>>((const __hip_bfloat16*)H, Wt, cvec, norm_s, T);
    k_agg128f<<<AGG_BLOCKS, 256, 0, stream>>>((const unsigned*)T, wsrt, rp, col, norm_d, b2, (unsigned*)H, bnp);
    k_bnred<<<64, 256, 0, stream>>>(bnp, bnp2);

    // Layer 3 (64 outputs) + log_softmax
    k_wprep<true><<<64, 64, 0, stream>>>(W3, bnp2, g2, be2, 64, Wt, cvec);
    k_gemm<__hip_bfloat16, 64><<<gemm_grid, 256, 0, stream>>>((const __hip_bfloat16*)H, Wt, cvec, norm_s, T);
    k_agg64f<<<AGG_BLOCKS, 256, 0, stream>>>((const __hip_bfloat16*)T, wsrt, rp, col, norm_d, b3, out);
}